// Round 4
// baseline (681075.146 us; speedup 1.0000x reference)
//
#include <hip/hip_runtime.h>
#include <hip/hip_cooperative_groups.h>

namespace cg = cooperative_groups;

#define Bb 64
#define Tt 256
#define Dd 1024
#define Hh 1024
#define HMm 256
#define Ee 64

__device__ __forceinline__ float b2f(unsigned short u){
    union{unsigned int i; float f;} v; v.i = ((unsigned int)u) << 16; return v.f;
}
__device__ __forceinline__ unsigned short f2bf(float f){
    union{float f; unsigned int i;} v; v.f = f;
    unsigned int x = v.i;
    unsigned int r = (x + 0x7fffu + ((x >> 16) & 1u)) >> 16;
    return (unsigned short)r;
}
__device__ __forceinline__ void up2(unsigned int u, float& lo, float& hi){
    union{unsigned int i; float f;} x, y;
    x.i = u << 16; y.i = u & 0xffff0000u; lo = x.f; hi = y.f;
}
__device__ __forceinline__ float sigf(float x){ return 1.f/(1.f + expf(-x)); }

__device__ __forceinline__ float ldT(const unsigned short* p){ return b2f(*p); }
__device__ __forceinline__ float ldT(const float* p){ return *p; }
__device__ __forceinline__ void stT(unsigned short* p, float v){ *p = f2bf(v); }
__device__ __forceinline__ void stT(float* p, float v){ *p = v; }

__device__ __forceinline__ void ld8(const unsigned short* p, float* f){
    uint4 u = *(const uint4*)(const void*)p;
    up2(u.x,f[0],f[1]); up2(u.y,f[2],f[3]); up2(u.z,f[4],f[5]); up2(u.w,f[6],f[7]);
}
__device__ __forceinline__ void ld8(const float* p, float* f){
    float4 a = *(const float4*)(const void*)p;
    float4 b = *(const float4*)(const void*)(p+4);
    f[0]=a.x; f[1]=a.y; f[2]=a.z; f[3]=a.w; f[4]=b.x; f[5]=b.y; f[6]=b.z; f[7]=b.w;
}
__device__ __forceinline__ float dot8(const float* a, const float* b, float acc){
    #pragma unroll
    for(int i=0;i<8;i++) acc += a[i]*b[i];
    return acc;
}

// ---- coherent (L1/L2-bypassing, L3-served) accesses for cross-block data ----
// Agent-scope relaxed atomics compile to sc0/sc1-flagged loads/stores on gfx95x:
// they bypass the non-coherent per-XCD L2s, making cross-XCD data coherent at
// the die-level L3 WITHOUT any barrier-time L2 invalidate. Weights keep normal
// cached loads and stay L2-warm across the whole kernel.
__device__ __forceinline__ float ld_c(const float* p){
    return __hip_atomic_load(p, __ATOMIC_RELAXED, __HIP_MEMORY_SCOPE_AGENT);
}
__device__ __forceinline__ void st_c(float* p, float v){
    __hip_atomic_store(p, v, __ATOMIC_RELAXED, __HIP_MEMORY_SCOPE_AGENT);
}
__device__ __forceinline__ void ld2_c(const float* p, float* f){
    union{unsigned long long u; float fv[2];} c;
    c.u = __hip_atomic_load((const unsigned long long*)(const void*)p,
                            __ATOMIC_RELAXED, __HIP_MEMORY_SCOPE_AGENT);
    f[0] = c.fv[0]; f[1] = c.fv[1];
}
__device__ __forceinline__ void ld4_c(const float* p, float* f){
    ld2_c(p, f); ld2_c(p + 2, f + 2);
}
__device__ __forceinline__ void ld8_c(const float* p, float* f){
    ld2_c(p, f); ld2_c(p + 2, f + 2); ld2_c(p + 4, f + 4); ld2_c(p + 6, f + 6);
}

// ---- custom grid barrier: sense-reversing, release-only (NO L2 invalidate).
// Release fetch_add drains vmcnt (all our st_c writes are at the L3 coherence
// point) and writes back any dirty lines; spin uses relaxed loads so no
// buffer_inv is ever emitted -> clean weight lines in L2 survive the barrier.
__device__ __forceinline__ void gbar(unsigned* cnt, unsigned* gen, int nb){
    __syncthreads();
    if(threadIdx.x == 0){
        asm volatile("" ::: "memory");
        unsigned g = __hip_atomic_load(gen, __ATOMIC_RELAXED, __HIP_MEMORY_SCOPE_AGENT);
        unsigned a = __hip_atomic_fetch_add(cnt, 1u, __ATOMIC_RELEASE, __HIP_MEMORY_SCOPE_AGENT);
        if(a == (unsigned)(nb - 1)){
            __hip_atomic_store(cnt, 0u, __ATOMIC_RELAXED, __HIP_MEMORY_SCOPE_AGENT);
            __hip_atomic_store(gen, g + 1u, __ATOMIC_RELEASE, __HIP_MEMORY_SCOPE_AGENT);
        }else{
            while(__hip_atomic_load(gen, __ATOMIC_RELAXED, __HIP_MEMORY_SCOPE_AGENT) == g)
                __builtin_amdgcn_s_sleep(32);
        }
        asm volatile("" ::: "memory");
    }
    __syncthreads();
}

// ---- dtype probe + barrier init ----
__global__ void k_detect(const unsigned short* __restrict__ x, int* __restrict__ flag,
                         unsigned* __restrict__ cnt, unsigned* __restrict__ gen){
    int tid = threadIdx.x;
    float v = fabsf(b2f(x[2 * tid]));
    bool in = (v > 1e-4f) && (v < 50.f);
    unsigned long long m = __ballot(in);
    if(tid == 0){
        *flag = (__popcll(m) >= 32) ? 0 : 1;  // 0 = bf16, 1 = f32
        *cnt = 0u; *gen = 0u;                 // barrier reset each launch/replay
    }
}

// ============================================================================
// BF16 path (verified earlier; does not run for f32 harness inputs).
// ============================================================================
__global__ __launch_bounds__(1024, 4) void coop_rnn_bf16(
    const unsigned short* x,
    const unsigned short* __restrict__ Wx, const unsigned short* __restrict__ Wh,
    const unsigned short* __restrict__ Wmx, const unsigned short* __restrict__ Wmh,
    const unsigned short* __restrict__ bm,
    const unsigned short* __restrict__ Wzx, const unsigned short* __restrict__ bzx,
    const unsigned short* __restrict__ Wzh, const unsigned short* __restrict__ bzh,
    const unsigned short* __restrict__ Wzb,
    const unsigned short* __restrict__ Px, const unsigned short* __restrict__ Ph,
    const unsigned short* __restrict__ Pb,
    unsigned short* out, float* ws, const int* flag)
{
    if(*flag != 0) return;
    cg::grid_group grid = cg::this_grid();

    float* h0   = ws;
    float* h1   = ws + 65536;
    float* cst  = ws + 131072;
    float* m0   = ws + 196608;
    float* m1   = ws + 212992;
    float* mcst = ws + 229376;
    float* z    = ws + 245760;
    unsigned short* xbuf16 = (unsigned short*)(ws + 294912);

    int tid = threadIdx.x, bid = blockIdx.x;

    __shared__ __align__(16) unsigned short sWx[16][4][264];
    __shared__ __align__(16) unsigned short sWh[16][4][264];
    __shared__ __align__(16) unsigned short sWmxX[4][4][264];
    __shared__ __align__(16) unsigned short sWmxH[4][4][264];
    __shared__ __align__(16) unsigned short sWmh[4][4][72];
    __shared__ __align__(16) unsigned short sWz[3][4][72];
    __shared__ __align__(16) unsigned short sP[3][4][64][4];
    __shared__ float sBm[4], sBz[2];
    __shared__ float sA[256];
    __shared__ float spre[1024];

    for(int l = 0; l < 2; l++){
        const unsigned short* xseq = l ? out : x;
        const unsigned short* Wx_l  = Wx  + (size_t)l * 4194304;
        const unsigned short* Wh_l  = Wh  + (size_t)l * 4194304;
        const unsigned short* Wmx_l = Wmx + (size_t)l * 2097152;
        const unsigned short* Wmh_l = Wmh + (size_t)l * 262144;
        const unsigned short* bm_l  = bm  + l * 1024;
        const unsigned short* Wz0 = Wzx + l * 65536;
        const unsigned short* Wz1 = Wzh + l * 65536;
        const unsigned short* Wz2 = Wzb + l * 65536;
        const unsigned short* bz0 = bzx + l * 256;
        const unsigned short* bz1 = bzh + l * 256;
        const unsigned short* Px_l = Px + l * 262144;
        const unsigned short* Ph_l = Ph + l * 262144;
        const unsigned short* Pb_l = Pb + l * 262144;

        {
            int gid = bid * 1024 + tid;
            if(gid < 65536){ h0[gid] = 0.f; cst[gid] = 0.f; }
            if(gid < 16384){ m0[gid] = 0.f; mcst[gid] = 0.f; }
        }

        for(int idx = tid; idx < 16384; idx += 1024){
            int rr = idx >> 10, k = idx & 1023;
            int g = rr >> 2, hh = rr & 3;
            size_t n = (size_t)(g * 1024 + bid * 4 + hh);
            sWx[rr][k >> 8][k & 255] = Wx_l[n * 1024 + k];
        }
        for(int idx = tid; idx < 16384; idx += 1024){
            int rr = idx >> 10, k = idx & 1023;
            int g = rr >> 2, hh = rr & 3;
            size_t n = (size_t)(g * 1024 + bid * 4 + hh);
            sWh[rr][k >> 8][k & 255] = Wh_l[n * 1024 + k];
        }
        for(int idx = tid; idx < 4096; idx += 1024){
            int r = idx >> 10, k = idx & 1023;
            size_t row = (size_t)(r * 256 + bid);
            sWmxX[r][k >> 8][k & 255] = Wmx_l[row * 2048 + k];
            sWmxH[r][k >> 8][k & 255] = Wmx_l[row * 2048 + 1024 + k];
        }
        {
            int r = tid >> 8, m = tid & 255;
            sWmh[r][m >> 6][m & 63] = Wmh_l[(size_t)(r * 256 + bid) * 256 + m];
        }
        if(tid < 768){
            int s_ = tid >> 8, m = tid & 255;
            const unsigned short* W = (s_ == 0) ? Wz0 : ((s_ == 1) ? Wz1 : Wz2);
            sWz[s_][m >> 6][m & 63] = W[m * 256 + bid];
        }
        {
            int g = tid >> 8, e = (tid >> 2) & 63, hh = tid & 3;
            int pi = (g * 64 + e) * 1024 + bid * 4 + hh;
            sP[0][g][e][hh] = Px_l[pi];
            sP[1][g][e][hh] = Ph_l[pi];
            sP[2][g][e][hh] = Pb_l[pi];
        }
        if(tid < 4) sBm[tid] = ldT(&bm_l[tid * 256 + bid]);
        if(tid == 4) sBz[0] = ldT(&bz0[bid]);
        if(tid == 5) sBz[1] = ldT(&bz1[bid]);

        float *hp = h0, *hn = h1, *mp = m0, *mn = m1;
        grid.sync();

        for(int t = 0; t < 256; t++){
            {
                int sg = bid * 1024 + tid;
                if(sg < 65536){
                    int xb = sg >> 10, xd = sg & 1023;
                    xbuf16[sg] = xseq[((size_t)xb * Tt + t) * Dd + xd];
                }

                int r  = tid >> 8;
                int b  = (tid >> 2) & 63;
                int ks = tid & 3;
                const unsigned short* wxp = &sWmxX[r][ks][0];
                const unsigned short* whp_ = &sWmxH[r][ks][0];
                const unsigned short* wmp = &sWmh[r][ks][0];
                const unsigned short* xr = xseq + ((size_t)b * Tt + t) * Dd + ks * 256;
                const float* hr = hp + b * 1024 + ks * 256;
                const float* mr = mp + b * 256 + ks * 64;
                float a0 = 0.f, a1 = 0.f, a2 = 0.f, a3 = 0.f;
                float wf[8], vf[8];
                for(int k = 0; k < 256; k += 16){
                    ld8(wxp + k, wf);     ld8(xr + k, vf);     a0 = dot8(wf, vf, a0);
                    ld8(wxp + k + 8, wf); ld8(xr + k + 8, vf); a1 = dot8(wf, vf, a1);
                }
                for(int k = 0; k < 256; k += 16){
                    ld8(whp_ + k, wf);     ld8(hr + k, vf);     a2 = dot8(wf, vf, a2);
                    ld8(whp_ + k + 8, wf); ld8(hr + k + 8, vf); a3 = dot8(wf, vf, a3);
                }
                for(int m = 0; m < 64; m += 16){
                    ld8(wmp + m, wf);     ld8(mr + m, vf);     a0 = dot8(wf, vf, a0);
                    ld8(wmp + m + 8, wf); ld8(mr + m + 8, vf); a1 = dot8(wf, vf, a1);
                }
                float a = (a0 + a1) + (a2 + a3);
                a += __shfl_xor(a, 1);
                a += __shfl_xor(a, 2);
                if(ks == 0) sA[r * 64 + b] = a + sBm[r];
            }
            __syncthreads();
            if(tid < 64){
                int b = tid;
                float mi = sA[b], mf = sA[64 + b], mg = sA[128 + b], mo = sA[192 + b];
                int idx = b * 256 + bid;
                float mc2 = sigf(mf) * mcst[idx] + sigf(mi) * tanhf(mg);
                mcst[idx] = mc2;
                mn[idx] = sigf(mo) * tanhf(mc2);
            }
            grid.sync();

            if(tid < 768){
                int s_ = tid >> 8, sub = tid & 255;
                int b = sub >> 2, ks = sub & 3;
                const unsigned short* wz = &sWz[s_][ks][0];
                const float* mr = mn + b * 256 + ks * 64;
                float acc = 0.f; float wf[8], vf[8];
                for(int m = 0; m < 64; m += 16){
                    ld8(wz + m, wf);     ld8(mr + m, vf);     acc = dot8(wf, vf, acc);
                    ld8(wz + m + 8, wf); ld8(mr + m + 8, vf); acc = dot8(wf, vf, acc);
                }
                acc += __shfl_xor(acc, 1);
                acc += __shfl_xor(acc, 2);
                if(ks == 0){
                    float biasv = (s_ == 0) ? sBz[0] : ((s_ == 1) ? sBz[1] : 0.f);
                    z[((s_ * 256) + bid) * 64 + b] = acc + biasv;
                }
            }
            grid.sync();

            {
                int r16 = tid >> 6;
                int g = r16 >> 2, hh = r16 & 3;
                int bg = (tid >> 2) & 15;
                int ks = tid & 3;
                int b0 = bg * 4;
                const unsigned short* wxr = &sWx[r16][ks][0];
                const unsigned short* whr = &sWh[r16][ks][0];
                float gx[4] = {0,0,0,0}, gh[4] = {0,0,0,0};
                for(int k = 0; k < 256; k += 8){
                    float wf[8]; ld8(wxr + k, wf);
                    #pragma unroll
                    for(int i = 0; i < 4; i++){
                        float xf[8]; ld8(xbuf16 + (b0 + i) * 1024 + ks * 256 + k, xf);
                        gx[i] = dot8(wf, xf, gx[i]);
                    }
                }
                for(int k = 0; k < 256; k += 8){
                    float wf[8]; ld8(whr + k, wf);
                    #pragma unroll
                    for(int i = 0; i < 4; i++){
                        float hf[8]; ld8(hp + (b0 + i) * 1024 + ks * 256 + k, hf);
                        gh[i] = dot8(wf, hf, gh[i]);
                    }
                }
                float dx[4] = {0,0,0,0}, dh[4] = {0,0,0,0}, db[4] = {0,0,0,0};
                int e0 = ks * 16;
                for(int e = e0; e < e0 + 16; e++){
                    int zc = g * 64 + e;
                    float pxv = b2f(sP[0][g][e][hh]);
                    float phv = b2f(sP[1][g][e][hh]);
                    float pbv = b2f(sP[2][g][e][hh]);
                    const float4 zx4 = *(const float4*)&z[(0 * 256 + zc) * 64 + b0];
                    const float4 zh4 = *(const float4*)&z[(1 * 256 + zc) * 64 + b0];
                    const float4 zb4 = *(const float4*)&z[(2 * 256 + zc) * 64 + b0];
                    dx[0] += zx4.x * pxv; dx[1] += zx4.y * pxv; dx[2] += zx4.z * pxv; dx[3] += zx4.w * pxv;
                    dh[0] += zh4.x * phv; dh[1] += zh4.y * phv; dh[2] += zh4.z * phv; dh[3] += zh4.w * phv;
                    db[0] += zb4.x * pbv; db[1] += zb4.y * pbv; db[2] += zb4.z * pbv; db[3] += zb4.w * pbv;
                }
                #pragma unroll
                for(int i = 0; i < 4; i++){
                    gx[i] += __shfl_xor(gx[i], 1); gx[i] += __shfl_xor(gx[i], 2);
                    gh[i] += __shfl_xor(gh[i], 1); gh[i] += __shfl_xor(gh[i], 2);
                    dx[i] += __shfl_xor(dx[i], 1); dx[i] += __shfl_xor(dx[i], 2);
                    dh[i] += __shfl_xor(dh[i], 1); dh[i] += __shfl_xor(dh[i], 2);
                    db[i] += __shfl_xor(db[i], 1); db[i] += __shfl_xor(db[i], 2);
                }
                if(ks == 0){
                    #pragma unroll
                    for(int i = 0; i < 4; i++)
                        spre[r16 * 64 + b0 + i] = dx[i] * gx[i] + dh[i] * gh[i] + db[i];
                }
            }
            __syncthreads();
            if(tid < 256){
                int hh = tid >> 6, b = tid & 63;
                float pi_ = spre[(0 * 4 + hh) * 64 + b];
                float pf_ = spre[(1 * 4 + hh) * 64 + b];
                float pg_ = spre[(2 * 4 + hh) * 64 + b];
                float po_ = spre[(3 * 4 + hh) * 64 + b];
                int h = bid * 4 + hh;
                int idx = b * 1024 + h;
                float c2 = sigf(pf_) * cst[idx] + sigf(pi_) * tanhf(pg_);
                float h2 = sigf(po_) * tanhf(c2);
                cst[idx] = c2;
                hn[idx] = h2;
                stT(&out[((size_t)b * Tt + t) * Dd + h], h2);
            }
            grid.sync();

            float* tp = hp; hp = hn; hn = tp;
            tp = mp; mp = mn; mn = tp;
        }
    }
}

// ============================================================================
// F32 path (the one that runs). Custom no-invalidate barrier; cross-block
// data via agent-scope (L3-coherent) accesses; weights L2-warm forever.
// LDS: sWx 66K + sWh 66K + sP 15K + sWz 3.2K + sA 1K + spre 4K = 155.2 KB.
// ============================================================================
__global__ __launch_bounds__(1024, 4) void coop_rnn_f32(
    const float* x,
    const float* __restrict__ Wx, const float* __restrict__ Wh,
    const float* __restrict__ Wmx, const float* __restrict__ Wmh, const float* __restrict__ bm,
    const float* __restrict__ Wzx, const float* __restrict__ bzx,
    const float* __restrict__ Wzh, const float* __restrict__ bzh, const float* __restrict__ Wzb,
    const float* __restrict__ Px, const float* __restrict__ Ph, const float* __restrict__ Pb,
    float* out, float* ws, const int* flag, unsigned* bcnt, unsigned* bgen)
{
    if(*flag != 1) return;

    float* h0   = ws;
    float* h1   = ws + 65536;
    float* cst  = ws + 131072;
    float* m0   = ws + 196608;
    float* m1   = ws + 212992;
    float* mcst = ws + 229376;
    float* z    = ws + 245760;   // [3][256][64] f32 (unit-major, batch-minor)
    float* xbuf = ws + 294912;   // [64][1024] f32 staged x_t

    int tid = threadIdx.x, bid = blockIdx.x;

    __shared__ __align__(16) float sWx[16][4][264];   // 67,584 B
    __shared__ __align__(16) float sWh[16][4][264];   // 67,584 B
    __shared__ __align__(16) float sP[3][4][64][5];   // 15,360 B
    __shared__ __align__(16) float sWz[3][4][68];     //  3,264 B
    __shared__ float sA[256];
    __shared__ float spre[1024];

    for(int l = 0; l < 2; l++){
        const float* xseq = l ? out : x;
        const float* Wx_l  = Wx  + (size_t)l * 4194304;
        const float* Wh_l  = Wh  + (size_t)l * 4194304;
        const float* Wmx_l = Wmx + (size_t)l * 2097152;
        const float* Wmh_l = Wmh + (size_t)l * 262144;
        const float* bm_l  = bm  + l * 1024;
        const float* Wz0 = Wzx + l * 65536;
        const float* Wz1 = Wzh + l * 65536;
        const float* Wz2 = Wzb + l * 65536;
        const float* bz0 = bzx + l * 256;
        const float* bz1 = bzh + l * 256;
        const float* Px_l = Px + l * 262144;
        const float* Ph_l = Ph + l * 262144;
        const float* Pb_l = Pb + l * 262144;

        // ---- zero states (coherent stores: straight to L3) ----
        {
            int gid = bid * 1024 + tid;
            if(gid < 65536){ st_c(&h0[gid], 0.f); st_c(&cst[gid], 0.f); }
            if(gid < 16384){ st_c(&m0[gid], 0.f); st_c(&mcst[gid], 0.f); }
        }

        // ---- LDS weight slices (normal cached loads -> also warms L2) ----
        for(int idx = tid; idx < 16384; idx += 1024){
            int rr = idx >> 10, k = idx & 1023;
            int g = rr >> 2, hh = rr & 3;
            size_t n = (size_t)(g * 1024 + bid * 4 + hh);
            sWx[rr][k >> 8][k & 255] = Wx_l[n * 1024 + k];
            sWh[rr][k >> 8][k & 255] = Wh_l[n * 1024 + k];
        }
        {
            int g = tid >> 8, e = (tid >> 2) & 63, hh = tid & 3;
            int pi = (g * 64 + e) * 1024 + bid * 4 + hh;
            sP[0][g][e][hh] = Px_l[pi];
            sP[1][g][e][hh] = Ph_l[pi];
            sP[2][g][e][hh] = Pb_l[pi];
        }
        if(tid < 768){
            int s_ = tid >> 8, m = tid & 255;
            const float* W = (s_ == 0) ? Wz0 : ((s_ == 1) ? Wz1 : Wz2);
            sWz[s_][m >> 6][m & 63] = W[m * 256 + bid];
        }

        float *hp = h0, *hn = h1, *mp = m0, *mn = m1;
        gbar(bcnt, bgen, 256);

        for(int t = 0; t < 256; t++){
            // ======== PHASE A: meta GEMM (Wmx/Wmh L2-warm) + stage xbuf ========
            {
                int sg = bid * 1024 + tid;   // block bid stages batch-row bid
                if(sg < 65536){
                    int xb = sg >> 10, xd = sg & 1023;
                    st_c(&xbuf[sg], ld_c(&xseq[((size_t)xb * Tt + t) * Dd + xd]));
                }
                int r  = tid >> 8;
                int b  = (tid >> 2) & 63;
                int ks = tid & 3;
                int row = r * 256 + bid;
                const float* wr = Wmx_l + (size_t)row * 2048;
                const float* wm = Wmh_l + (size_t)row * 256;
                const float* xr = xseq + ((size_t)b * Tt + t) * Dd;
                const float* hr = hp + b * 1024;
                const float* mr = mp + b * 256;
                float a0 = 0.f, a1 = 0.f, a2 = 0.f, a3 = 0.f;
                float wf[8], vf[8];
                int k0 = ks * 256;
                for(int k = k0; k < k0 + 256; k += 16){
                    ld8(wr + k, wf);      ld8_c(xr + k, vf);      a0 = dot8(wf, vf, a0);
                    ld8(wr + k + 8, wf);  ld8_c(xr + k + 8, vf);  a1 = dot8(wf, vf, a1);
                }
                for(int k = k0; k < k0 + 256; k += 16){
                    ld8(wr + 1024 + k, wf);     ld8_c(hr + k, vf);     a2 = dot8(wf, vf, a2);
                    ld8(wr + 1024 + k + 8, wf); ld8_c(hr + k + 8, vf); a3 = dot8(wf, vf, a3);
                }
                int ms = ks * 64;
                for(int m = ms; m < ms + 64; m += 16){
                    ld8(wm + m, wf);     ld8_c(mr + m, vf);     a0 = dot8(wf, vf, a0);
                    ld8(wm + m + 8, wf); ld8_c(mr + m + 8, vf); a1 = dot8(wf, vf, a1);
                }
                float a = (a0 + a1) + (a2 + a3);
                a += __shfl_xor(a, 1);
                a += __shfl_xor(a, 2);
                if(ks == 0) sA[r * 64 + b] = a + ldT(&bm_l[row]);
            }
            __syncthreads();
            if(tid < 64){
                int b = tid;
                float mi = sA[b], mf = sA[64 + b], mg = sA[128 + b], mo = sA[192 + b];
                int idx = b * 256 + bid;
                float mc2 = sigf(mf) * ld_c(&mcst[idx]) + sigf(mi) * tanhf(mg);
                st_c(&mcst[idx], mc2);
                st_c(&mn[idx], sigf(mo) * tanhf(mc2));
            }
            gbar(bcnt, bgen, 256);

            // ======== PHASE Z: block bid owns unit-column bid (Wz in LDS) ========
            if(tid < 768){
                int s_ = tid >> 8, sub = tid & 255;
                int b = sub >> 2, ks = sub & 3;
                const float* wz = &sWz[s_][ks][0];
                const float* mr = mn + b * 256 + ks * 64;
                float acc = 0.f; float wf[8], vf[8];
                for(int m = 0; m < 64; m += 16){
                    ld8(wz + m, wf);     ld8_c(mr + m, vf);     acc = dot8(wf, vf, acc);
                    ld8(wz + m + 8, wf); ld8_c(mr + m + 8, vf); acc = dot8(wf, vf, acc);
                }
                acc += __shfl_xor(acc, 1);
                acc += __shfl_xor(acc, 2);
                if(ks == 0){
                    float biasv = (s_ == 0) ? ldT(&bz0[bid]) : ((s_ == 1) ? ldT(&bz1[bid]) : 0.f);
                    st_c(&z[((s_ * 256) + bid) * 64 + b], acc + biasv);
                }
            }
            gbar(bcnt, bgen, 256);

            // ======== PHASE B: pre = dx*gx + dh*gh + db (LDS weights) ========
            {
                int r16 = tid >> 6;
                int g = r16 >> 2, hh = r16 & 3;
                int bg = (tid >> 2) & 15;
                int ks = tid & 3;
                int b0 = bg * 4;
                const float* wxr = &sWx[r16][ks][0];
                const float* whr = &sWh[r16][ks][0];
                float gx[4] = {0,0,0,0}, gh[4] = {0,0,0,0};
                for(int k = 0; k < 256; k += 8){
                    float wf[8]; ld8(wxr + k, wf);
                    #pragma unroll
                    for(int i = 0; i < 4; i++){
                        float xf[8]; ld8_c(xbuf + (b0 + i) * 1024 + ks * 256 + k, xf);
                        gx[i] = dot8(wf, xf, gx[i]);
                    }
                }
                for(int k = 0; k < 256; k += 8){
                    float wf[8]; ld8(whr + k, wf);
                    #pragma unroll
                    for(int i = 0; i < 4; i++){
                        float hf[8]; ld8_c(hp + (b0 + i) * 1024 + ks * 256 + k, hf);
                        gh[i] = dot8(wf, hf, gh[i]);
                    }
                }
                float dx[4] = {0,0,0,0}, dh[4] = {0,0,0,0}, db[4] = {0,0,0,0};
                int e0 = ks * 16;
                for(int e = e0; e < e0 + 16; e++){
                    int zc = g * 64 + e;
                    float pxv = sP[0][g][e][hh];
                    float phv = sP[1][g][e][hh];
                    float pbv = sP[2][g][e][hh];
                    float zx4[4], zh4[4], zb4[4];
                    ld4_c(&z[(0 * 256 + zc) * 64 + b0], zx4);
                    ld4_c(&z[(1 * 256 + zc) * 64 + b0], zh4);
                    ld4_c(&z[(2 * 256 + zc) * 64 + b0], zb4);
                    #pragma unroll
                    for(int i = 0; i < 4; i++){
                        dx[i] += zx4[i] * pxv;
                        dh[i] += zh4[i] * phv;
                        db[i] += zb4[i] * pbv;
                    }
                }
                #pragma unroll
                for(int i = 0; i < 4; i++){
                    gx[i] += __shfl_xor(gx[i], 1); gx[i] += __shfl_xor(gx[i], 2);
                    gh[i] += __shfl_xor(gh[i], 1); gh[i] += __shfl_xor(gh[i], 2);
                    dx[i] += __shfl_xor(dx[i], 1); dx[i] += __shfl_xor(dx[i], 2);
                    dh[i] += __shfl_xor(dh[i], 1); dh[i] += __shfl_xor(dh[i], 2);
                    db[i] += __shfl_xor(db[i], 1); db[i] += __shfl_xor(db[i], 2);
                }
                if(ks == 0){
                    #pragma unroll
                    for(int i = 0; i < 4; i++)
                        spre[r16 * 64 + b0 + i] = dx[i] * gx[i] + dh[i] * gh[i] + db[i];
                }
            }
            __syncthreads();
            if(tid < 256){
                int hh = tid >> 6, b = tid & 63;
                float pi_ = spre[(0 * 4 + hh) * 64 + b];
                float pf_ = spre[(1 * 4 + hh) * 64 + b];
                float pg_ = spre[(2 * 4 + hh) * 64 + b];
                float po_ = spre[(3 * 4 + hh) * 64 + b];
                int h = bid * 4 + hh;
                int idx = b * 1024 + h;
                float c2 = sigf(pf_) * ld_c(&cst[idx]) + sigf(pi_) * tanhf(pg_);
                float h2 = sigf(po_) * tanhf(c2);
                st_c(&cst[idx], c2);
                st_c(&hn[idx], h2);
                st_c(&out[((size_t)b * Tt + t) * Dd + h], h2);
            }
            gbar(bcnt, bgen, 256);

            float* tp = hp; hp = hn; hn = tp;
            tp = mp; mp = mn; mn = tp;
        }
    }
}

static void launch_bf16(void* const* d_in, void* d_out, float* ws, int* flag, hipStream_t stream){
    const unsigned short* xp   = (const unsigned short*)d_in[0];
    const unsigned short* Wxp  = (const unsigned short*)d_in[1];
    const unsigned short* Whp  = (const unsigned short*)d_in[2];
    const unsigned short* Wmxp = (const unsigned short*)d_in[3];
    const unsigned short* Wmhp = (const unsigned short*)d_in[4];
    const unsigned short* bmp  = (const unsigned short*)d_in[5];
    const unsigned short* Wzxp = (const unsigned short*)d_in[6];
    const unsigned short* bzxp = (const unsigned short*)d_in[7];
    const unsigned short* Wzhp = (const unsigned short*)d_in[8];
    const unsigned short* bzhp = (const unsigned short*)d_in[9];
    const unsigned short* Wzbp = (const unsigned short*)d_in[10];
    const unsigned short* Pxp  = (const unsigned short*)d_in[11];
    const unsigned short* Php  = (const unsigned short*)d_in[12];
    const unsigned short* Pbp  = (const unsigned short*)d_in[13];
    unsigned short* outp = (unsigned short*)d_out;
    void* args[] = {
        (void*)&xp, (void*)&Wxp, (void*)&Whp, (void*)&Wmxp, (void*)&Wmhp, (void*)&bmp,
        (void*)&Wzxp, (void*)&bzxp, (void*)&Wzhp, (void*)&bzhp, (void*)&Wzbp,
        (void*)&Pxp, (void*)&Php, (void*)&Pbp, (void*)&outp, (void*)&ws, (void*)&flag
    };
    hipLaunchCooperativeKernel((void*)coop_rnn_bf16, dim3(256), dim3(1024), args, 0, stream);
}

static void launch_f32(void* const* d_in, void* d_out, float* ws, int* flag,
                       unsigned* bcnt, unsigned* bgen, hipStream_t stream){
    const float* xp   = (const float*)d_in[0];
    const float* Wxp  = (const float*)d_in[1];
    const float* Whp  = (const float*)d_in[2];
    const float* Wmxp = (const float*)d_in[3];
    const float* Wmhp = (const float*)d_in[4];
    const float* bmp  = (const float*)d_in[5];
    const float* Wzxp = (const float*)d_in[6];
    const float* bzxp = (const float*)d_in[7];
    const float* Wzhp = (const float*)d_in[8];
    const float* bzhp = (const float*)d_in[9];
    const float* Wzbp = (const float*)d_in[10];
    const float* Pxp  = (const float*)d_in[11];
    const float* Php  = (const float*)d_in[12];
    const float* Pbp  = (const float*)d_in[13];
    float* outp = (float*)d_out;
    void* args[] = {
        (void*)&xp, (void*)&Wxp, (void*)&Whp, (void*)&Wmxp, (void*)&Wmhp, (void*)&bmp,
        (void*)&Wzxp, (void*)&bzxp, (void*)&Wzhp, (void*)&bzhp, (void*)&Wzbp,
        (void*)&Pxp, (void*)&Php, (void*)&Pbp, (void*)&outp, (void*)&ws, (void*)&flag,
        (void*)&bcnt, (void*)&bgen
    };
    hipLaunchCooperativeKernel((void*)coop_rnn_f32, dim3(256), dim3(1024), args, 0, stream);
}

extern "C" void kernel_launch(void* const* d_in, const int* in_sizes, int n_in,
                              void* d_out, int out_size, void* d_ws, size_t ws_size,
                              hipStream_t stream) {
    (void)in_sizes; (void)n_in; (void)out_size; (void)ws_size;
    float* ws = (float*)d_ws;
    int* flag = (int*)(ws + 360448);
    unsigned* bcnt = (unsigned*)(ws + 360464);   // own 64B line
    unsigned* bgen = (unsigned*)(ws + 360480);   // own 64B line

    k_detect<<<1, 64, 0, stream>>>((const unsigned short*)d_in[0], flag, bcnt, bgen);
    launch_bf16(d_in, d_out, ws, flag, stream);
    launch_f32(d_in, d_out, ws, flag, bcnt, bgen, stream);
}

// Round 5
// 235701.099 us; speedup vs baseline: 2.8896x; 2.8896x over previous
//
#include <hip/hip_runtime.h>
#include <hip/hip_cooperative_groups.h>

namespace cg = cooperative_groups;

#define Bb 64
#define Tt 256
#define Dd 1024
#define Hh 1024
#define HMm 256
#define Ee 64

__device__ __forceinline__ float b2f(unsigned short u){
    union{unsigned int i; float f;} v; v.i = ((unsigned int)u) << 16; return v.f;
}
__device__ __forceinline__ unsigned short f2bf(float f){
    union{float f; unsigned int i;} v; v.f = f;
    unsigned int x = v.i;
    unsigned int r = (x + 0x7fffu + ((x >> 16) & 1u)) >> 16;
    return (unsigned short)r;
}
__device__ __forceinline__ void up2(unsigned int u, float& lo, float& hi){
    union{unsigned int i; float f;} x, y;
    x.i = u << 16; y.i = u & 0xffff0000u; lo = x.f; hi = y.f;
}
__device__ __forceinline__ float sigf(float x){ return 1.f/(1.f + expf(-x)); }

__device__ __forceinline__ float ldT(const unsigned short* p){ return b2f(*p); }
__device__ __forceinline__ float ldT(const float* p){ return *p; }
__device__ __forceinline__ void stT(unsigned short* p, float v){ *p = f2bf(v); }
__device__ __forceinline__ void stT(float* p, float v){ *p = v; }

__device__ __forceinline__ void ld8(const unsigned short* p, float* f){
    uint4 u = *(const uint4*)(const void*)p;
    up2(u.x,f[0],f[1]); up2(u.y,f[2],f[3]); up2(u.z,f[4],f[5]); up2(u.w,f[6],f[7]);
}
__device__ __forceinline__ void ld8(const float* p, float* f){
    float4 a = *(const float4*)(const void*)p;
    float4 b = *(const float4*)(const void*)(p+4);
    f[0]=a.x; f[1]=a.y; f[2]=a.z; f[3]=a.w; f[4]=b.x; f[5]=b.y; f[6]=b.z; f[7]=b.w;
}
__device__ __forceinline__ float dot8(const float* a, const float* b, float acc){
    #pragma unroll
    for(int i=0;i<8;i++) acc += a[i]*b[i];
    return acc;
}
__device__ __forceinline__ float redsum64(float s){
    #pragma unroll
    for(int o = 1; o < 64; o <<= 1) s += __shfl_xor(s, o);
    return s;
}

// ---- dtype probe: even-indexed u16 as bf16 is ~N(0,1) iff buffer is bf16 ----
__global__ void k_detect(const unsigned short* __restrict__ x, int* __restrict__ flag){
    int tid = threadIdx.x;
    float v = fabsf(b2f(x[2 * tid]));
    bool in = (v > 1e-4f) && (v < 50.f);
    unsigned long long m = __ballot(in);
    if(tid == 0) *flag = (__popcll(m) >= 32) ? 0 : 1;  // 0 = bf16, 1 = f32
}

// ============================================================================
// BF16 path (kept from earlier verified round; does not run for f32 inputs).
// ============================================================================
__global__ __launch_bounds__(1024, 4) void coop_rnn_bf16(
    const unsigned short* x,
    const unsigned short* __restrict__ Wx, const unsigned short* __restrict__ Wh,
    const unsigned short* __restrict__ Wmx, const unsigned short* __restrict__ Wmh,
    const unsigned short* __restrict__ bm,
    const unsigned short* __restrict__ Wzx, const unsigned short* __restrict__ bzx,
    const unsigned short* __restrict__ Wzh, const unsigned short* __restrict__ bzh,
    const unsigned short* __restrict__ Wzb,
    const unsigned short* __restrict__ Px, const unsigned short* __restrict__ Ph,
    const unsigned short* __restrict__ Pb,
    unsigned short* out, float* ws, const int* flag)
{
    if(*flag != 0) return;
    cg::grid_group grid = cg::this_grid();

    float* h0   = ws;
    float* h1   = ws + 65536;
    float* cst  = ws + 131072;
    float* m0   = ws + 196608;
    float* m1   = ws + 212992;
    float* mcst = ws + 229376;
    float* z    = ws + 245760;
    unsigned short* xbuf16 = (unsigned short*)(ws + 294912);

    int tid = threadIdx.x, bid = blockIdx.x;

    __shared__ __align__(16) unsigned short sWx[16][4][264];
    __shared__ __align__(16) unsigned short sWh[16][4][264];
    __shared__ __align__(16) unsigned short sWmxX[4][4][264];
    __shared__ __align__(16) unsigned short sWmxH[4][4][264];
    __shared__ __align__(16) unsigned short sWmh[4][4][72];
    __shared__ __align__(16) unsigned short sWz[3][4][72];
    __shared__ __align__(16) unsigned short sP[3][4][64][4];
    __shared__ float sBm[4], sBz[2];
    __shared__ float sA[256];
    __shared__ float spre[1024];

    for(int l = 0; l < 2; l++){
        const unsigned short* xseq = l ? out : x;
        const unsigned short* Wx_l  = Wx  + (size_t)l * 4194304;
        const unsigned short* Wh_l  = Wh  + (size_t)l * 4194304;
        const unsigned short* Wmx_l = Wmx + (size_t)l * 2097152;
        const unsigned short* Wmh_l = Wmh + (size_t)l * 262144;
        const unsigned short* bm_l  = bm  + l * 1024;
        const unsigned short* Wz0 = Wzx + l * 65536;
        const unsigned short* Wz1 = Wzh + l * 65536;
        const unsigned short* Wz2 = Wzb + l * 65536;
        const unsigned short* bz0 = bzx + l * 256;
        const unsigned short* bz1 = bzh + l * 256;
        const unsigned short* Px_l = Px + l * 262144;
        const unsigned short* Ph_l = Ph + l * 262144;
        const unsigned short* Pb_l = Pb + l * 262144;

        {
            int gid = bid * 1024 + tid;
            if(gid < 65536){ h0[gid] = 0.f; cst[gid] = 0.f; }
            if(gid < 16384){ m0[gid] = 0.f; mcst[gid] = 0.f; }
        }

        for(int idx = tid; idx < 16384; idx += 1024){
            int rr = idx >> 10, k = idx & 1023;
            int g = rr >> 2, hh = rr & 3;
            size_t n = (size_t)(g * 1024 + bid * 4 + hh);
            sWx[rr][k >> 8][k & 255] = Wx_l[n * 1024 + k];
        }
        for(int idx = tid; idx < 16384; idx += 1024){
            int rr = idx >> 10, k = idx & 1023;
            int g = rr >> 2, hh = rr & 3;
            size_t n = (size_t)(g * 1024 + bid * 4 + hh);
            sWh[rr][k >> 8][k & 255] = Wh_l[n * 1024 + k];
        }
        for(int idx = tid; idx < 4096; idx += 1024){
            int r = idx >> 10, k = idx & 1023;
            size_t row = (size_t)(r * 256 + bid);
            sWmxX[r][k >> 8][k & 255] = Wmx_l[row * 2048 + k];
            sWmxH[r][k >> 8][k & 255] = Wmx_l[row * 2048 + 1024 + k];
        }
        {
            int r = tid >> 8, m = tid & 255;
            sWmh[r][m >> 6][m & 63] = Wmh_l[(size_t)(r * 256 + bid) * 256 + m];
        }
        if(tid < 768){
            int s_ = tid >> 8, m = tid & 255;
            const unsigned short* W = (s_ == 0) ? Wz0 : ((s_ == 1) ? Wz1 : Wz2);
            sWz[s_][m >> 6][m & 63] = W[m * 256 + bid];
        }
        {
            int g = tid >> 8, e = (tid >> 2) & 63, hh = tid & 3;
            int pi = (g * 64 + e) * 1024 + bid * 4 + hh;
            sP[0][g][e][hh] = Px_l[pi];
            sP[1][g][e][hh] = Ph_l[pi];
            sP[2][g][e][hh] = Pb_l[pi];
        }
        if(tid < 4) sBm[tid] = ldT(&bm_l[tid * 256 + bid]);
        if(tid == 4) sBz[0] = ldT(&bz0[bid]);
        if(tid == 5) sBz[1] = ldT(&bz1[bid]);

        float *hp = h0, *hn = h1, *mp = m0, *mn = m1;
        grid.sync();

        for(int t = 0; t < 256; t++){
            {
                int sg = bid * 1024 + tid;
                if(sg < 65536){
                    int xb = sg >> 10, xd = sg & 1023;
                    xbuf16[sg] = xseq[((size_t)xb * Tt + t) * Dd + xd];
                }
                int r  = tid >> 8;
                int b  = (tid >> 2) & 63;
                int ks = tid & 3;
                const unsigned short* wxp = &sWmxX[r][ks][0];
                const unsigned short* whp_ = &sWmxH[r][ks][0];
                const unsigned short* wmp = &sWmh[r][ks][0];
                const unsigned short* xr = xseq + ((size_t)b * Tt + t) * Dd + ks * 256;
                const float* hr = hp + b * 1024 + ks * 256;
                const float* mr = mp + b * 256 + ks * 64;
                float a0 = 0.f, a1 = 0.f, a2 = 0.f, a3 = 0.f;
                float wf[8], vf[8];
                for(int k = 0; k < 256; k += 16){
                    ld8(wxp + k, wf);     ld8(xr + k, vf);     a0 = dot8(wf, vf, a0);
                    ld8(wxp + k + 8, wf); ld8(xr + k + 8, vf); a1 = dot8(wf, vf, a1);
                }
                for(int k = 0; k < 256; k += 16){
                    ld8(whp_ + k, wf);     ld8(hr + k, vf);     a2 = dot8(wf, vf, a2);
                    ld8(whp_ + k + 8, wf); ld8(hr + k + 8, vf); a3 = dot8(wf, vf, a3);
                }
                for(int m = 0; m < 64; m += 16){
                    ld8(wmp + m, wf);     ld8(mr + m, vf);     a0 = dot8(wf, vf, a0);
                    ld8(wmp + m + 8, wf); ld8(mr + m + 8, vf); a1 = dot8(wf, vf, a1);
                }
                float a = (a0 + a1) + (a2 + a3);
                a += __shfl_xor(a, 1);
                a += __shfl_xor(a, 2);
                if(ks == 0) sA[r * 64 + b] = a + sBm[r];
            }
            __syncthreads();
            if(tid < 64){
                int b = tid;
                float mi = sA[b], mf = sA[64 + b], mg = sA[128 + b], mo = sA[192 + b];
                int idx = b * 256 + bid;
                float mc2 = sigf(mf) * mcst[idx] + sigf(mi) * tanhf(mg);
                mcst[idx] = mc2;
                mn[idx] = sigf(mo) * tanhf(mc2);
            }
            grid.sync();

            if(tid < 768){
                int s_ = tid >> 8, sub = tid & 255;
                int b = sub >> 2, ks = sub & 3;
                const unsigned short* wz = &sWz[s_][ks][0];
                const float* mr = mn + b * 256 + ks * 64;
                float acc = 0.f; float wf[8], vf[8];
                for(int m = 0; m < 64; m += 16){
                    ld8(wz + m, wf);     ld8(mr + m, vf);     acc = dot8(wf, vf, acc);
                    ld8(wz + m + 8, wf); ld8(mr + m + 8, vf); acc = dot8(wf, vf, acc);
                }
                acc += __shfl_xor(acc, 1);
                acc += __shfl_xor(acc, 2);
                if(ks == 0){
                    float biasv = (s_ == 0) ? sBz[0] : ((s_ == 1) ? sBz[1] : 0.f);
                    z[((s_ * 256) + bid) * 64 + b] = acc + biasv;
                }
            }
            grid.sync();

            {
                int r16 = tid >> 6;
                int g = r16 >> 2, hh = r16 & 3;
                int bg = (tid >> 2) & 15;
                int ks = tid & 3;
                int b0 = bg * 4;
                const unsigned short* wxr = &sWx[r16][ks][0];
                const unsigned short* whr = &sWh[r16][ks][0];
                float gx[4] = {0,0,0,0}, gh[4] = {0,0,0,0};
                for(int k = 0; k < 256; k += 8){
                    float wf[8]; ld8(wxr + k, wf);
                    #pragma unroll
                    for(int i = 0; i < 4; i++){
                        float xf[8]; ld8(xbuf16 + (b0 + i) * 1024 + ks * 256 + k, xf);
                        gx[i] = dot8(wf, xf, gx[i]);
                    }
                }
                for(int k = 0; k < 256; k += 8){
                    float wf[8]; ld8(whr + k, wf);
                    #pragma unroll
                    for(int i = 0; i < 4; i++){
                        float hf[8]; ld8(hp + (b0 + i) * 1024 + ks * 256 + k, hf);
                        gh[i] = dot8(wf, hf, gh[i]);
                    }
                }
                float dx[4] = {0,0,0,0}, dh[4] = {0,0,0,0}, db[4] = {0,0,0,0};
                int e0 = ks * 16;
                for(int e = e0; e < e0 + 16; e++){
                    int zc = g * 64 + e;
                    float pxv = b2f(sP[0][g][e][hh]);
                    float phv = b2f(sP[1][g][e][hh]);
                    float pbv = b2f(sP[2][g][e][hh]);
                    const float4 zx4 = *(const float4*)&z[(0 * 256 + zc) * 64 + b0];
                    const float4 zh4 = *(const float4*)&z[(1 * 256 + zc) * 64 + b0];
                    const float4 zb4 = *(const float4*)&z[(2 * 256 + zc) * 64 + b0];
                    dx[0] += zx4.x * pxv; dx[1] += zx4.y * pxv; dx[2] += zx4.z * pxv; dx[3] += zx4.w * pxv;
                    dh[0] += zh4.x * phv; dh[1] += zh4.y * phv; dh[2] += zh4.z * phv; dh[3] += zh4.w * phv;
                    db[0] += zb4.x * pbv; db[1] += zb4.y * pbv; db[2] += zb4.z * pbv; db[3] += zb4.w * pbv;
                }
                #pragma unroll
                for(int i = 0; i < 4; i++){
                    gx[i] += __shfl_xor(gx[i], 1); gx[i] += __shfl_xor(gx[i], 2);
                    gh[i] += __shfl_xor(gh[i], 1); gh[i] += __shfl_xor(gh[i], 2);
                    dx[i] += __shfl_xor(dx[i], 1); dx[i] += __shfl_xor(dx[i], 2);
                    dh[i] += __shfl_xor(dh[i], 1); dh[i] += __shfl_xor(dh[i], 2);
                    db[i] += __shfl_xor(db[i], 1); db[i] += __shfl_xor(db[i], 2);
                }
                if(ks == 0){
                    #pragma unroll
                    for(int i = 0; i < 4; i++)
                        spre[r16 * 64 + b0 + i] = dx[i] * gx[i] + dh[i] * gh[i] + db[i];
                }
            }
            __syncthreads();
            if(tid < 256){
                int hh = tid >> 6, b = tid & 63;
                float pi_ = spre[(0 * 4 + hh) * 64 + b];
                float pf_ = spre[(1 * 4 + hh) * 64 + b];
                float pg_ = spre[(2 * 4 + hh) * 64 + b];
                float po_ = spre[(3 * 4 + hh) * 64 + b];
                int h = bid * 4 + hh;
                int idx = b * 1024 + h;
                float c2 = sigf(pf_) * cst[idx] + sigf(pi_) * tanhf(pg_);
                float h2 = sigf(po_) * tanhf(c2);
                cst[idx] = c2;
                hn[idx] = h2;
                stT(&out[((size_t)b * Tt + t) * Dd + h], h2);
            }
            grid.sync();

            float* tp = hp; hp = hn; hn = tp;
            tp = mp; mp = mn; mn = tp;
        }
    }
}

// ============================================================================
// F32 path (runs). 512 threads, launch_bounds(512,2) -> up to 256 VGPR.
// Phase 1: wave-GEMV meta (Wmx slice in REGISTERS, loaded once/layer) fused
//          with gx/gh k-loops (LDS Wx/Wh; results -> sgx/sgh LDS).
// Phase 2: z GEMV (Wz in LDS, z transposed [3][256][64]).
// Phase 3: e-dots (deep float2 z loads) + combine + LSTM update.
// LDS = 160,768 B. cg grid.sync (3/step).
// ============================================================================
__global__ __launch_bounds__(512, 2) void coop_rnn_f32(
    const float* x,
    const float* __restrict__ Wx, const float* __restrict__ Wh,
    const float* __restrict__ Wmx, const float* __restrict__ Wmh, const float* __restrict__ bm,
    const float* __restrict__ Wzx, const float* __restrict__ bzx,
    const float* __restrict__ Wzh, const float* __restrict__ bzh, const float* __restrict__ Wzb,
    const float* __restrict__ Px, const float* __restrict__ Ph, const float* __restrict__ Pb,
    float* out, float* ws, const int* flag)
{
    if(*flag != 1) return;
    cg::grid_group grid = cg::this_grid();

    float* h0   = ws;
    float* h1   = ws + 65536;
    float* cst  = ws + 131072;
    float* m0   = ws + 196608;
    float* m1   = ws + 212992;
    float* mcst = ws + 229376;
    float* z    = ws + 245760;   // [3][256][64] f32 (unit-major, batch-minor)

    int tid = threadIdx.x, bid = blockIdx.x;
    int wave = tid >> 6, lane = tid & 63;

    __shared__ __align__(16) float sWx[16][2][520];   // 66,560 B
    __shared__ __align__(16) float sWh[16][2][520];   // 66,560 B
    __shared__ __align__(16) float sP[3][4][64][4];   // 12,288 B (broadcast reads)
    __shared__ __align__(16) float sWz[3][2][128];    //  3,072 B (broadcast reads)
    __shared__ float sgx[1024];                       //  4,096 B [16 rows][64 b]
    __shared__ float sgh[1024];                       //  4,096 B
    __shared__ float spre[1024];                      //  4,096 B (also aliases sA)
    float* sA = spre;                                 // phase-1-only use

    for(int l = 0; l < 2; l++){
        const float* xseq = l ? out : x;
        const float* Wx_l  = Wx  + (size_t)l * 4194304;
        const float* Wh_l  = Wh  + (size_t)l * 4194304;
        const float* Wmx_l = Wmx + (size_t)l * 2097152;
        const float* Wmh_l = Wmh + (size_t)l * 262144;
        const float* bm_l  = bm  + l * 1024;
        const float* Wz0 = Wzx + l * 65536;
        const float* Wz1 = Wzh + l * 65536;
        const float* Wz2 = Wzb + l * 65536;
        const float* bz0 = bzx + l * 256;
        const float* bz1 = bzh + l * 256;
        const float* Px_l = Px + l * 262144;
        const float* Ph_l = Ph + l * 262144;
        const float* Pb_l = Pb + l * 262144;

        // ---- zero states ----
        {
            int gid = bid * 512 + tid;                 // [0, 131072)
            if(gid < 65536){ h0[gid] = 0.f; cst[gid] = 0.f; }
            if(gid < 16384){ m0[gid] = 0.f; mcst[gid] = 0.f; }
        }

        // ---- LDS weight slices (once per layer) ----
        for(int idx = tid; idx < 16384; idx += 512){
            int rr = idx >> 10, k = idx & 1023;
            size_t n = (size_t)((rr >> 2) * 1024 + bid * 4 + (rr & 3));
            sWx[rr][k >> 9][k & 511] = Wx_l[n * 1024 + k];
            sWh[rr][k >> 9][k & 511] = Wh_l[n * 1024 + k];
        }
        for(int idx = tid; idx < 3072; idx += 512){
            int s_ = idx >> 10, rem = idx & 1023;
            int g = rem >> 8, e = (rem >> 2) & 63, hh = rem & 3;
            int pi = (g * 64 + e) * 1024 + bid * 4 + hh;
            const float* P = (s_ == 0) ? Px_l : ((s_ == 1) ? Ph_l : Pb_l);
            sP[s_][g][e][hh] = P[pi];
        }
        for(int idx = tid; idx < 768; idx += 512){
            int s_ = idx >> 8, m = idx & 255;
            const float* W = (s_ == 0) ? Wz0 : ((s_ == 1) ? Wz1 : Wz2);
            sWz[s_][m >> 7][m & 127] = W[m * 256 + bid];
        }

        // ---- per-wave register weights for meta GEMV (once per layer) ----
        // row = r*256+bid; lane covers xcat[lane*32 .. +31] (x|h concat) + mh[lane*4..+3]
        int rA = wave >> 1, bhalf = wave & 1;
        int rowA = rA * 256 + bid;
        float wa[32], wm4[4], bmv;
        {
            const float* wp = Wmx_l + (size_t)rowA * 2048 + lane * 32;
            ld8(wp, wa); ld8(wp + 8, wa + 8); ld8(wp + 16, wa + 16); ld8(wp + 24, wa + 24);
            const float4 q4 = *(const float4*)(Wmh_l + (size_t)rowA * 256 + lane * 4);
            wm4[0] = q4.x; wm4[1] = q4.y; wm4[2] = q4.z; wm4[3] = q4.w;
            bmv = bm_l[rowA];
        }
        float bz0v = bz0[bid], bz1v = bz1[bid];

        float *hp = h0, *hn = h1, *mp = m0, *mn = m1;
        grid.sync();

        for(int t = 0; t < 256; t++){
            // ================= PHASE 1: meta GEMV + gx/gh =================
            {
                // --- meta GEMV: wave (rA, bhalf) does 32 batches ---
                const float* xbase = xseq + (size_t)t * 1024;   // + b*262144 + lane*32
                int lx = lane * 32;
                float va[32], vm[4], vb[32], vn[4];
                int b0 = bhalf * 32;
                #define LOADV(VA, VM, bb) { \
                    const float* vp = (lane < 32) ? (xbase + (size_t)(bb) * 262144 + lx) \
                                                  : (hp + (bb) * 1024 + lx - 1024); \
                    ld8(vp, VA); ld8(vp + 8, VA + 8); ld8(vp + 16, VA + 16); ld8(vp + 24, VA + 24); \
                    const float4 q = *(const float4*)(mp + (bb) * 256 + lane * 4); \
                    VM[0] = q.x; VM[1] = q.y; VM[2] = q.z; VM[3] = q.w; }
                LOADV(va, vm, b0)
                for(int i = 0; i < 32; i += 2){
                    int b = b0 + i;
                    LOADV(vb, vn, b + 1)
                    float s = 0.f;
                    #pragma unroll
                    for(int j = 0; j < 32; j++) s += wa[j] * va[j];
                    #pragma unroll
                    for(int j = 0; j < 4; j++)  s += wm4[j] * vm[j];
                    s = redsum64(s);
                    if(lane == 0) sA[rA * 64 + b] = s + bmv;
                    if(i + 2 < 32){ LOADV(va, vm, b + 2) }
                    float s2 = 0.f;
                    #pragma unroll
                    for(int j = 0; j < 32; j++) s2 += wa[j] * vb[j];
                    #pragma unroll
                    for(int j = 0; j < 4; j++)  s2 += wm4[j] * vn[j];
                    s2 = redsum64(s2);
                    if(lane == 0) sA[rA * 64 + b + 1] = s2 + bmv;
                }
                #undef LOADV

                // --- gx/gh k-loops (LDS weights, 8-deep global v batching) ---
                int r16 = tid >> 5;
                int bg = (tid >> 1) & 15, ks = tid & 1;
                int b0g = bg * 4;
                const float* wxr = &sWx[r16][ks][0];
                const float* whr = &sWh[r16][ks][0];
                float gx[4] = {0,0,0,0}, gh[4] = {0,0,0,0};
                for(int k = 0; k < 512; k += 16){
                    float w0[8], w1[8]; ld8(wxr + k, w0); ld8(wxr + k + 8, w1);
                    float xf[4][8], xg[4][8];
                    #pragma unroll
                    for(int i = 0; i < 4; i++){
                        const float* xp = xseq + ((size_t)(b0g + i) * Tt + t) * 1024 + ks * 512 + k;
                        ld8(xp, xf[i]); ld8(xp + 8, xg[i]);
                    }
                    #pragma unroll
                    for(int i = 0; i < 4; i++){
                        gx[i] = dot8(w0, xf[i], gx[i]);
                        gx[i] = dot8(w1, xg[i], gx[i]);
                    }
                }
                for(int k = 0; k < 512; k += 16){
                    float w0[8], w1[8]; ld8(whr + k, w0); ld8(whr + k + 8, w1);
                    float hf[4][8], hg[4][8];
                    #pragma unroll
                    for(int i = 0; i < 4; i++){
                        const float* hpp = hp + (b0g + i) * 1024 + ks * 512 + k;
                        ld8(hpp, hf[i]); ld8(hpp + 8, hg[i]);
                    }
                    #pragma unroll
                    for(int i = 0; i < 4; i++){
                        gh[i] = dot8(w0, hf[i], gh[i]);
                        gh[i] = dot8(w1, hg[i], gh[i]);
                    }
                }
                #pragma unroll
                for(int i = 0; i < 4; i++){
                    gx[i] += __shfl_xor(gx[i], 1);
                    gh[i] += __shfl_xor(gh[i], 1);
                }
                if(ks == 0){
                    #pragma unroll
                    for(int i = 0; i < 4; i++){
                        sgx[r16 * 64 + b0g + i] = gx[i];
                        sgh[r16 * 64 + b0g + i] = gh[i];
                    }
                }
            }
            __syncthreads();
            if(tid < 64){
                int b = tid;
                float mi = sA[b], mf = sA[64 + b], mg = sA[128 + b], mo = sA[192 + b];
                int idx = b * 256 + bid;
                float mc2 = sigf(mf) * mcst[idx] + sigf(mi) * tanhf(mg);
                mcst[idx] = mc2;
                mn[idx] = sigf(mo) * tanhf(mc2);
            }
            grid.sync();

            // ================= PHASE 2: z GEMV (unit column bid) =================
            if(tid < 384){
                int s_ = tid >> 7, sub = tid & 127;
                int b = sub >> 1, ks = sub & 1;
                const float* wz = &sWz[s_][ks][0];
                const float* mr = mn + b * 256 + ks * 128;
                float acc = 0.f;
                for(int m = 0; m < 128; m += 32){
                    float v0[8], v1[8], v2[8], v3[8];
                    ld8(mr + m, v0); ld8(mr + m + 8, v1);
                    ld8(mr + m + 16, v2); ld8(mr + m + 24, v3);
                    float w0[8], w1[8], w2[8], w3[8];
                    ld8(wz + m, w0); ld8(wz + m + 8, w1);
                    ld8(wz + m + 16, w2); ld8(wz + m + 24, w3);
                    acc = dot8(w0, v0, acc); acc = dot8(w1, v1, acc);
                    acc = dot8(w2, v2, acc); acc = dot8(w3, v3, acc);
                }
                acc += __shfl_xor(acc, 1);
                if(ks == 0){
                    float biasv = (s_ == 0) ? bz0v : ((s_ == 1) ? bz1v : 0.f);
                    z[((s_ * 256) + bid) * 64 + b] = acc + biasv;
                }
            }
            grid.sync();

            // ================= PHASE 3: e-dots + combine + LSTM update =================
            {
                int r16 = tid >> 5, bp = tid & 31;
                int g = r16 >> 2, hh = r16 & 3;
                int b = bp * 2;
                float dxx = 0.f, dxy = 0.f, dhx = 0.f, dhy = 0.f, dbx = 0.f, dby = 0.f;
                for(int e8 = 0; e8 < 64; e8 += 8){
                    float2 zx[8], zh[8], zb[8];
                    #pragma unroll
                    for(int j = 0; j < 8; j++){
                        int zc = g * 64 + e8 + j;
                        zx[j] = *(const float2*)&z[(0 * 256 + zc) * 64 + b];
                        zh[j] = *(const float2*)&z[(1 * 256 + zc) * 64 + b];
                        zb[j] = *(const float2*)&z[(2 * 256 + zc) * 64 + b];
                    }
                    #pragma unroll
                    for(int j = 0; j < 8; j++){
                        int e = e8 + j;
                        float px = sP[0][g][e][hh];
                        float ph = sP[1][g][e][hh];
                        float pb = sP[2][g][e][hh];
                        dxx += zx[j].x * px; dxy += zx[j].y * px;
                        dhx += zh[j].x * ph; dhy += zh[j].y * ph;
                        dbx += zb[j].x * pb; dby += zb[j].y * pb;
                    }
                }
                float gx0 = sgx[r16 * 64 + b],     gh0 = sgh[r16 * 64 + b];
                float gx1 = sgx[r16 * 64 + b + 1], gh1 = sgh[r16 * 64 + b + 1];
                spre[r16 * 64 + b]     = dxx * gx0 + dhx * gh0 + dbx;
                spre[r16 * 64 + b + 1] = dxy * gx1 + dhy * gh1 + dby;
            }
            __syncthreads();
            if(tid < 256){
                int hh = tid >> 6, b = tid & 63;
                float pi_ = spre[(0 * 4 + hh) * 64 + b];
                float pf_ = spre[(1 * 4 + hh) * 64 + b];
                float pg_ = spre[(2 * 4 + hh) * 64 + b];
                float po_ = spre[(3 * 4 + hh) * 64 + b];
                int h = bid * 4 + hh;
                int idx = b * 1024 + h;
                float c2 = sigf(pf_) * cst[idx] + sigf(pi_) * tanhf(pg_);
                float h2 = sigf(po_) * tanhf(c2);
                cst[idx] = c2;
                hn[idx] = h2;
                stT(&out[((size_t)b * Tt + t) * Dd + h], h2);
            }
            grid.sync();

            float* tp = hp; hp = hn; hn = tp;
            tp = mp; mp = mn; mn = tp;
        }
    }
}

static void launch_bf16(void* const* d_in, void* d_out, float* ws, int* flag, hipStream_t stream){
    const unsigned short* xp   = (const unsigned short*)d_in[0];
    const unsigned short* Wxp  = (const unsigned short*)d_in[1];
    const unsigned short* Whp  = (const unsigned short*)d_in[2];
    const unsigned short* Wmxp = (const unsigned short*)d_in[3];
    const unsigned short* Wmhp = (const unsigned short*)d_in[4];
    const unsigned short* bmp  = (const unsigned short*)d_in[5];
    const unsigned short* Wzxp = (const unsigned short*)d_in[6];
    const unsigned short* bzxp = (const unsigned short*)d_in[7];
    const unsigned short* Wzhp = (const unsigned short*)d_in[8];
    const unsigned short* bzhp = (const unsigned short*)d_in[9];
    const unsigned short* Wzbp = (const unsigned short*)d_in[10];
    const unsigned short* Pxp  = (const unsigned short*)d_in[11];
    const unsigned short* Php  = (const unsigned short*)d_in[12];
    const unsigned short* Pbp  = (const unsigned short*)d_in[13];
    unsigned short* outp = (unsigned short*)d_out;
    void* args[] = {
        (void*)&xp, (void*)&Wxp, (void*)&Whp, (void*)&Wmxp, (void*)&Wmhp, (void*)&bmp,
        (void*)&Wzxp, (void*)&bzxp, (void*)&Wzhp, (void*)&bzhp, (void*)&Wzbp,
        (void*)&Pxp, (void*)&Php, (void*)&Pbp, (void*)&outp, (void*)&ws, (void*)&flag
    };
    hipLaunchCooperativeKernel((void*)coop_rnn_bf16, dim3(256), dim3(1024), args, 0, stream);
}

static void launch_f32(void* const* d_in, void* d_out, float* ws, int* flag, hipStream_t stream){
    const float* xp   = (const float*)d_in[0];
    const float* Wxp  = (const float*)d_in[1];
    const float* Whp  = (const float*)d_in[2];
    const float* Wmxp = (const float*)d_in[3];
    const float* Wmhp = (const float*)d_in[4];
    const float* bmp  = (const float*)d_in[5];
    const float* Wzxp = (const float*)d_in[6];
    const float* bzxp = (const float*)d_in[7];
    const float* Wzhp = (const float*)d_in[8];
    const float* bzhp = (const float*)d_in[9];
    const float* Wzbp = (const float*)d_in[10];
    const float* Pxp  = (const float*)d_in[11];
    const float* Php  = (const float*)d_in[12];
    const float* Pbp  = (const float*)d_in[13];
    float* outp = (float*)d_out;
    void* args[] = {
        (void*)&xp, (void*)&Wxp, (void*)&Whp, (void*)&Wmxp, (void*)&Wmhp, (void*)&bmp,
        (void*)&Wzxp, (void*)&bzxp, (void*)&Wzhp, (void*)&bzhp, (void*)&Wzbp,
        (void*)&Pxp, (void*)&Php, (void*)&Pbp, (void*)&outp, (void*)&ws, (void*)&flag
    };
    hipLaunchCooperativeKernel((void*)coop_rnn_f32, dim3(256), dim3(512), args, 0, stream);
}

extern "C" void kernel_launch(void* const* d_in, const int* in_sizes, int n_in,
                              void* d_out, int out_size, void* d_ws, size_t ws_size,
                              hipStream_t stream) {
    (void)in_sizes; (void)n_in; (void)out_size; (void)ws_size;
    float* ws = (float*)d_ws;
    int* flag = (int*)(ws + 360448);

    k_detect<<<1, 64, 0, stream>>>((const unsigned short*)d_in[0], flag);
    launch_bf16(d_in, d_out, ws, flag, stream);
    launch_f32(d_in, d_out, ws, flag, stream);
}